// Round 4
// baseline (104.901 us; speedup 1.0000x reference)
//
#include <hip/hip_runtime.h>

#define NEGINF -1000000000.0f

typedef __attribute__((ext_vector_type(4))) float f32x4;
typedef _Float16 half8 __attribute__((ext_vector_type(8)));
typedef _Float16 half4 __attribute__((ext_vector_type(4)));

constexpr int Bn = 64, Cn = 1024, Qn = 128, Dn = 128;
constexpr int QSTR = 136;   // halves; 272 B rows -> 2-way (free) b128 bank pattern
constexpr int CSTR = 132;   // floats; 528 B rows for cq bounce

// LDS map (bytes):
//   0      qrow [128][136] fp16 = 34816   } overlaid by cq [128][132] f32 = 67584 (phase 5+)
//   34816  qT2  [128][136] fp16 = 34816   } overlaid by partf 4096 (phase 4)
//   69632  wfull 384 f
//   71168  qts 128 f
//   71680  cts 128 f
//   72192  mloc 128 f
//   72704  wv 128 f
//   73216  red 16 f
//   73280  q2cs 128 f
// total 73792 -> exactly 2 blocks/CU -> all 512 blocks co-resident (barrier-safe)

__global__ void reset_kernel(unsigned* __restrict__ cnt) {
    cnt[threadIdx.x] = 0u;
}

__global__ __launch_bounds__(256, 2) void fused_kernel(
    const float* __restrict__ ctx, const float* __restrict__ qry,
    const float* __restrict__ W, const float* __restrict__ mask,
    float* __restrict__ out, float* __restrict__ ws_part,
    float* __restrict__ ws_ms, unsigned* __restrict__ cnt)
{
    __shared__ char smem[73792];
    _Float16* qrow = (_Float16*)smem;
    _Float16* qT2  = (_Float16*)(smem + 34816);
    float* wfull = (float*)(smem + 69632);
    float* qts   = (float*)(smem + 71168);
    float* cts   = (float*)(smem + 71680);
    float* mloc  = (float*)(smem + 72192);
    float* wv    = (float*)(smem + 72704);
    float* red   = (float*)(smem + 73216);
    float* q2cs  = (float*)(smem + 73280);
    float* partf = (float*)(smem + 34816);
    float* cq    = (float*)smem;

    const int b = blockIdx.y, cg = blockIdx.x, c0 = cg * 128;
    const int t = threadIdx.x;
    const float* ctxB = ctx + (size_t)b * Cn * Dn;
    const float* qryB = qry + (size_t)b * Qn * Dn;

    for (int i = t; i < 384; i += 256) wfull[i] = W[i];
    __syncthreads();

    // ---- phase 1a: stage query fp16 (row-major + bijection-transposed); qterm(+mask)
    {
        int q = t >> 1, h = t & 1;
        const float* qr = qryB + q * Dn + h * 64;
        int p = ((q >> 5) << 5) + 8 * ((q >> 2) & 3) + (q & 3) + 4 * ((q >> 4) & 1);
        float acc = 0.f;
        for (int j = 0; j < 64; j += 4) {
            f32x4 v = *(const f32x4*)(qr + j);
            int d = h * 64 + j;
            acc += v.x * wfull[128 + d] + v.y * wfull[128 + d + 1]
                 + v.z * wfull[128 + d + 2] + v.w * wfull[128 + d + 3];
            half4 hv;
            hv[0] = (_Float16)v.x; hv[1] = (_Float16)v.y;
            hv[2] = (_Float16)v.z; hv[3] = (_Float16)v.w;
            *(half4*)&qrow[q * QSTR + d] = hv;
            qT2[(d + 0) * QSTR + p] = hv[0];
            qT2[(d + 1) * QSTR + p] = hv[1];
            qT2[(d + 2) * QSTR + p] = hv[2];
            qT2[(d + 3) * QSTR + p] = hv[3];
        }
        acc += __shfl_xor(acc, 1);
        if (h == 0) qts[q] = acc + (1.0f - mask[b * Qn + q]) * NEGINF;
    }
    // ---- phase 1b: c_term for this ctile (warms L1/L2 with the tile)
    {
        int c = t >> 1, h = t & 1;
        const float* cr = ctxB + (size_t)(c0 + c) * Dn + h * 64;
        float acc = 0.f;
        for (int j = 0; j < 64; j += 4) {
            f32x4 v = *(const f32x4*)(cr + j);
            int d = h * 64 + j;
            acc += v.x * wfull[d] + v.y * wfull[d + 1] + v.z * wfull[d + 2] + v.w * wfull[d + 3];
        }
        acc += __shfl_xor(acc, 1);
        if (h == 0) cts[c] = acc;
    }
    __syncthreads();

    const int wave = t >> 6, lane = t & 63, g = lane >> 4, l15 = lane & 15;
    const int cw = wave * 32;

    // ---- phase 2: mm1  S^T[q][c], A=query (LDS fp16), B=ctx*w_s (hi/lo fp16)
    f32x4 acc1[8][2] = {};
#pragma unroll
    for (int kk = 0; kk < 4; ++kk) {
        const int dbase = kk * 32 + g * 8;
        f32x4 w0 = *(const f32x4*)&wfull[256 + dbase];
        f32x4 w1 = *(const f32x4*)&wfull[256 + dbase + 4];
        half8 ah[2], al[2];
#pragma unroll
        for (int nt = 0; nt < 2; ++nt) {
            const float* p = ctxB + (size_t)(c0 + cw + nt * 16 + l15) * Dn + dbase;
            f32x4 v0 = *(const f32x4*)p, v1 = *(const f32x4*)(p + 4);
            float av[8] = {v0.x * w0.x, v0.y * w0.y, v0.z * w0.z, v0.w * w0.w,
                           v1.x * w1.x, v1.y * w1.y, v1.z * w1.z, v1.w * w1.w};
#pragma unroll
            for (int j = 0; j < 8; ++j) {
                _Float16 hh = (_Float16)av[j];
                ah[nt][j] = hh;
                al[nt][j] = (_Float16)(av[j] - (float)hh);
            }
        }
#pragma unroll
        for (int mt = 0; mt < 8; ++mt) {
            half8 qf = *(const half8*)&qrow[(mt * 16 + l15) * QSTR + dbase];
#pragma unroll
            for (int nt = 0; nt < 2; ++nt) {
                acc1[mt][nt] = __builtin_amdgcn_mfma_f32_16x16x32_f16(qf, ah[nt], acc1[mt][nt], 0, 0, 0);
                acc1[mt][nt] = __builtin_amdgcn_mfma_f32_16x16x32_f16(qf, al[nt], acc1[mt][nt], 0, 0, 0);
            }
        }
    }

    // ---- +q_term(+mask); softmax over q per column; mloc = colmax + c_term
#pragma unroll
    for (int mt = 0; mt < 8; ++mt)
#pragma unroll
        for (int r = 0; r < 4; ++r) {
            float qv = qts[mt * 16 + g * 4 + r];
            acc1[mt][0][r] += qv;
            acc1[mt][1][r] += qv;
        }

    float psum[2];
#pragma unroll
    for (int nt = 0; nt < 2; ++nt) {
        float mx = -3.4e38f;
#pragma unroll
        for (int mt = 0; mt < 8; ++mt)
#pragma unroll
            for (int r = 0; r < 4; ++r) mx = fmaxf(mx, acc1[mt][nt][r]);
        mx = fmaxf(mx, __shfl_xor(mx, 16));
        mx = fmaxf(mx, __shfl_xor(mx, 32));
        float sum = 0.f;
#pragma unroll
        for (int mt = 0; mt < 8; ++mt)
#pragma unroll
            for (int r = 0; r < 4; ++r) {
                float pv = __expf(acc1[mt][nt][r] - mx);
                acc1[mt][nt][r] = pv;
                sum += pv;
            }
        sum += __shfl_xor(sum, 16);
        sum += __shfl_xor(sum, 32);
        psum[nt] = sum;
        int cl = cw + nt * 16 + l15;
        if (g == 0) mloc[cl] = mx + cts[cl];
    }

    half8 pa[4][2];
#pragma unroll
    for (int kk2 = 0; kk2 < 4; ++kk2)
#pragma unroll
        for (int nt = 0; nt < 2; ++nt)
#pragma unroll
            for (int j = 0; j < 8; ++j)
                pa[kk2][nt][j] = (_Float16)acc1[2 * kk2 + (j >> 2)][nt][j & 3];

    float inv[2][4];
#pragma unroll
    for (int nt = 0; nt < 2; ++nt)
#pragma unroll
        for (int r = 0; r < 4; ++r)
            inv[nt][r] = 1.0f / __shfl(psum[nt], g * 4 + r);

    // ---- phase 3: mm2  c2q[c][d] = sum_q P[c][q] query[q][d]
    f32x4 acc2[2][8] = {};
#pragma unroll
    for (int kk2 = 0; kk2 < 4; ++kk2)
#pragma unroll
        for (int ntD = 0; ntD < 8; ++ntD) {
            half8 qb = *(const half8*)&qT2[(ntD * 16 + l15) * QSTR + kk2 * 32 + 8 * g];
#pragma unroll
            for (int nt1 = 0; nt1 < 2; ++nt1)
                acc2[nt1][ntD] = __builtin_amdgcn_mfma_f32_16x16x32_f16(pa[kk2][nt1], qb, acc2[nt1][ntD], 0, 0, 0);
        }
    __syncthreads();   // qT2 dead; mloc complete

    // ---- phase 4: local q2c partial; keep ctx tile slice in registers
    float Mloc;
    {
        float v = (t < 128) ? mloc[t] : -3.4e38f;
        float m = v;
#pragma unroll
        for (int off = 1; off < 64; off <<= 1) m = fmaxf(m, __shfl_xor(m, off));
        if (lane == 0) red[wave] = m;
        __syncthreads();
        Mloc = fmaxf(fmaxf(red[0], red[1]), fmaxf(red[2], red[3]));
        float e = (t < 128) ? __expf(v - Mloc) : 0.f;
        if (t < 128) wv[t] = e;
        float s = e;
#pragma unroll
        for (int off = 1; off < 64; off <<= 1) s += __shfl_xor(s, off);
        if (lane == 0) red[4 + wave] = s;
        __syncthreads();
    }
    float Sloc = red[4] + red[5] + red[6] + red[7];

    const int grp = t >> 5, d4 = (t & 31) * 4;
    f32x4 cvr[16];
    {
        const float* cb = ctxB + (size_t)(c0 + grp * 16) * Dn;
        f32x4 a = {};
#pragma unroll
        for (int i = 0; i < 16; ++i) {
            cvr[i] = *(const f32x4*)(cb + (size_t)i * Dn + d4);
            float w = wv[grp * 16 + i];
            a.x += w * cvr[i].x; a.y += w * cvr[i].y;
            a.z += w * cvr[i].z; a.w += w * cvr[i].w;
        }
        *(f32x4*)&partf[grp * 128 + d4] = a;
        __syncthreads();
        if (t < 128) {
            float s = 0.f;
#pragma unroll
            for (int g2 = 0; g2 < 8; ++g2) s += partf[g2 * 128 + t];
            __hip_atomic_store(&ws_part[((size_t)(b * 8 + cg)) * 128 + t], s,
                               __ATOMIC_RELAXED, __HIP_MEMORY_SCOPE_AGENT);
        }
        if (t == 0) {
            __hip_atomic_store(&ws_ms[(b * 8 + cg) * 2 + 0], Mloc,
                               __ATOMIC_RELAXED, __HIP_MEMORY_SCOPE_AGENT);
            __hip_atomic_store(&ws_ms[(b * 8 + cg) * 2 + 1], Sloc,
                               __ATOMIC_RELAXED, __HIP_MEMORY_SCOPE_AGENT);
        }
    }
    __syncthreads();   // partf reads done -> cq may overlay
    if (t == 0) {
        __threadfence();
        __hip_atomic_fetch_add(&cnt[b], 1u, __ATOMIC_RELEASE, __HIP_MEMORY_SCOPE_AGENT);
    }

    // ---- phase 5: stage c2q into LDS (overlaps the barrier wait)
#pragma unroll
    for (int nt1 = 0; nt1 < 2; ++nt1)
#pragma unroll
        for (int r = 0; r < 4; ++r) {
            int c = cw + nt1 * 16 + g * 4 + r;
            float is = inv[nt1][r];
#pragma unroll
            for (int ntD = 0; ntD < 8; ++ntD)
                cq[c * CSTR + ntD * 16 + l15] = acc2[nt1][ntD][r] * is;
        }

    // ---- phase 6: per-batch barrier (8 blocks, all co-resident), combine q2c
    if (t == 0) {
        while (__hip_atomic_load(&cnt[b], __ATOMIC_ACQUIRE, __HIP_MEMORY_SCOPE_AGENT) < 8u)
            __builtin_amdgcn_s_sleep(2);
        __threadfence();
    }
    __syncthreads();
    if (t < 128) {
        float Mg = -3.4e38f;
        float msv[16];
#pragma unroll
        for (int i = 0; i < 16; ++i)
            msv[i] = __hip_atomic_load(&ws_ms[b * 16 + i], __ATOMIC_RELAXED, __HIP_MEMORY_SCOPE_AGENT);
#pragma unroll
        for (int i = 0; i < 8; ++i) Mg = fmaxf(Mg, msv[2 * i]);
        float num = 0.f, den = 0.f;
#pragma unroll
        for (int i = 0; i < 8; ++i) {
            float e = __expf(msv[2 * i] - Mg);
            num += e * __hip_atomic_load(&ws_part[((size_t)(b * 8 + i)) * 128 + t],
                                         __ATOMIC_RELAXED, __HIP_MEMORY_SCOPE_AGENT);
            den += e * msv[2 * i + 1];
        }
        q2cs[t] = num / den;
    }
    __syncthreads();

    // ---- phase 7: one-pass epilogue, all 4 columns, no ctx re-read
    {
        f32x4 qv = *(const f32x4*)&q2cs[d4];
#pragma unroll
        for (int i = 0; i < 16; ++i) {
            int c = grp * 16 + i;
            f32x4 cv = cvr[i];
            f32x4 cqv = *(const f32x4*)&cq[c * CSTR + d4];
            float* orow = out + ((size_t)(b * Cn + c0 + c)) * 512;
            *(f32x4*)(orow + d4) = cv;
            *(f32x4*)(orow + 128 + d4) = cqv;
            f32x4 p2, p3;
            p2.x = cv.x * cqv.x; p2.y = cv.y * cqv.y; p2.z = cv.z * cqv.z; p2.w = cv.w * cqv.w;
            p3.x = cv.x * qv.x;  p3.y = cv.y * qv.y;  p3.z = cv.z * qv.z;  p3.w = cv.w * qv.w;
            *(f32x4*)(orow + 256 + d4) = p2;
            *(f32x4*)(orow + 384 + d4) = p3;
        }
    }
}

extern "C" void kernel_launch(void* const* d_in, const int* in_sizes, int n_in,
                              void* d_out, int out_size, void* d_ws, size_t ws_size,
                              hipStream_t stream) {
    const float* ctx  = (const float*)d_in[0];
    const float* qry  = (const float*)d_in[1];
    const float* W    = (const float*)d_in[2];
    const float* mask = (const float*)d_in[3];
    float* out = (float*)d_out;

    float* ws_part = (float*)d_ws;                          // 64*8*128 f32
    float* ws_ms   = ws_part + (size_t)Bn * 8 * 128;        // 64*8*2 f32
    unsigned* cnt  = (unsigned*)(ws_ms + (size_t)Bn * 16);  // 64 u32

    reset_kernel<<<dim3(1), 64, 0, stream>>>(cnt);
    fused_kernel<<<dim3(8, Bn), 256, 0, stream>>>(ctx, qry, W, mask, out, ws_part, ws_ms, cnt);
}

// Round 5
// 51.483 us; speedup vs baseline: 2.0376x; 2.0376x over previous
//
#include <hip/hip_runtime.h>

#define NEGINF -1000000000.0f

typedef __attribute__((ext_vector_type(4))) float f32x4;
typedef _Float16 half8 __attribute__((ext_vector_type(8)));
typedef _Float16 half4 __attribute__((ext_vector_type(4)));

constexpr int Bn = 64, Cn = 1024, Qn = 128, Dn = 128;
constexpr int QSTR = 136;   // halves; 272 B rows -> 2-way (free) b128 bank pattern
constexpr int CSTR = 132;   // floats; 528 B rows for cq bounce

// LDS map (bytes), total 72768 -> 2 blocks/CU (145.5 KB of 160):
//   0      qrow [128][136] fp16 = 34816  } overlaid by cq [128][132] f32 = 67584 (phase 5+)
//   34816  qT2  [128][136] fp16 = 34816  } overlaid by partf [16][128] f32 = 8192 (phase 4)
//   69632  wfull 384 f (1536)
//   71168  qts  128 f
//   71680  mloc 128 f
//   72192  wv   128 f
//   72704  red  16 f (64)

__global__ __launch_bounds__(512, 4) void k1_kernel(
    const float* __restrict__ ctx, const float* __restrict__ qry,
    const float* __restrict__ W, const float* __restrict__ mask,
    float* __restrict__ out, float* __restrict__ ws_part, float* __restrict__ ws_ms)
{
    __shared__ char smem[72768];
    _Float16* qrow = (_Float16*)smem;
    _Float16* qT2  = (_Float16*)(smem + 34816);
    float* wfull = (float*)(smem + 69632);
    float* qts   = (float*)(smem + 71168);
    float* mloc  = (float*)(smem + 71680);
    float* wv    = (float*)(smem + 72192);
    float* red   = (float*)(smem + 72704);
    float* partf = (float*)(smem + 34816);  // after mm2
    float* cq    = (float*)smem;            // after q2c partial

    const int b = blockIdx.y, cg = blockIdx.x, c0 = cg * 128;
    const int t = threadIdx.x;
    const float* ctxB = ctx + (size_t)b * Cn * Dn;
    const float* qryB = qry + (size_t)b * Qn * Dn;

    if (t < 384) wfull[t] = W[t];
    __syncthreads();

    // ---- phase 1: stage query fp16 (row-major + bijection-transposed); qterm(+mask)
    {
        int q = t >> 2, h = t & 3;
        const float* qr = qryB + q * Dn + h * 32;
        int p = ((q >> 5) << 5) + 8 * ((q >> 2) & 3) + (q & 3) + 4 * ((q >> 4) & 1);
        float acc = 0.f;
        for (int j = 0; j < 32; j += 4) {
            f32x4 v = *(const f32x4*)(qr + j);
            int d = h * 32 + j;
            acc += v.x * wfull[128 + d] + v.y * wfull[128 + d + 1]
                 + v.z * wfull[128 + d + 2] + v.w * wfull[128 + d + 3];
            half4 hv;
            hv[0] = (_Float16)v.x; hv[1] = (_Float16)v.y;
            hv[2] = (_Float16)v.z; hv[3] = (_Float16)v.w;
            *(half4*)&qrow[q * QSTR + d] = hv;
            qT2[(d + 0) * QSTR + p] = hv[0];
            qT2[(d + 1) * QSTR + p] = hv[1];
            qT2[(d + 2) * QSTR + p] = hv[2];
            qT2[(d + 3) * QSTR + p] = hv[3];
        }
        acc += __shfl_xor(acc, 1);
        acc += __shfl_xor(acc, 2);
        if (h == 0) qts[q] = acc + (1.0f - mask[b * Qn + q]) * NEGINF;
    }
    __syncthreads();

    const int wave = t >> 6, lane = t & 63, g = lane >> 4, l15 = lane & 15;
    const int cw = wave * 16;
    const int cl = cw + l15;   // this lane's ctx row within the 128-tile

    // ---- phase 2: mm1  S^T[q][c] with fused c_term
    f32x4 acc1[8] = {};
    float cterm = 0.f;
#pragma unroll
    for (int kk = 0; kk < 4; ++kk) {
        const int dbase = kk * 32 + g * 8;
        const float* pc = ctxB + (size_t)(c0 + cl) * Dn + dbase;
        f32x4 v0 = *(const f32x4*)pc, v1 = *(const f32x4*)(pc + 4);
        f32x4 s0 = *(const f32x4*)&wfull[256 + dbase], s1 = *(const f32x4*)&wfull[256 + dbase + 4];
        f32x4 c0w = *(const f32x4*)&wfull[dbase], c1w = *(const f32x4*)&wfull[dbase + 4];
        cterm += v0.x * c0w.x + v0.y * c0w.y + v0.z * c0w.z + v0.w * c0w.w
               + v1.x * c1w.x + v1.y * c1w.y + v1.z * c1w.z + v1.w * c1w.w;
        float av[8] = {v0.x * s0.x, v0.y * s0.y, v0.z * s0.z, v0.w * s0.w,
                       v1.x * s1.x, v1.y * s1.y, v1.z * s1.z, v1.w * s1.w};
        half8 ah, al;
#pragma unroll
        for (int j = 0; j < 8; ++j) {
            _Float16 hh = (_Float16)av[j];
            ah[j] = hh;
            al[j] = (_Float16)(av[j] - (float)hh);
        }
#pragma unroll
        for (int mt = 0; mt < 8; ++mt) {
            half8 qf = *(const half8*)&qrow[(mt * 16 + l15) * QSTR + dbase];
            acc1[mt] = __builtin_amdgcn_mfma_f32_16x16x32_f16(qf, ah, acc1[mt], 0, 0, 0);
            acc1[mt] = __builtin_amdgcn_mfma_f32_16x16x32_f16(qf, al, acc1[mt], 0, 0, 0);
        }
    }
    cterm += __shfl_xor(cterm, 16);
    cterm += __shfl_xor(cterm, 32);   // now all lanes hold c_term for row cl

    // ---- phase 3: +q_term(+mask); softmax over q per column
#pragma unroll
    for (int mt = 0; mt < 8; ++mt)
#pragma unroll
        for (int r = 0; r < 4; ++r) acc1[mt][r] += qts[mt * 16 + g * 4 + r];

    float mx = -3.4e38f;
#pragma unroll
    for (int mt = 0; mt < 8; ++mt)
#pragma unroll
        for (int r = 0; r < 4; ++r) mx = fmaxf(mx, acc1[mt][r]);
    mx = fmaxf(mx, __shfl_xor(mx, 16));
    mx = fmaxf(mx, __shfl_xor(mx, 32));
    float sum = 0.f;
#pragma unroll
    for (int mt = 0; mt < 8; ++mt)
#pragma unroll
        for (int r = 0; r < 4; ++r) {
            float pv = __expf(acc1[mt][r] - mx);
            acc1[mt][r] = pv;
            sum += pv;
        }
    sum += __shfl_xor(sum, 16);
    sum += __shfl_xor(sum, 32);
    if (g == 0) mloc[cl] = mx + cterm;

    // pack P^T into A-frags (bijection k = 4g+(j&3)+16(j>>2)); inv colsums
    half8 pa[4];
#pragma unroll
    for (int kk2 = 0; kk2 < 4; ++kk2)
#pragma unroll
        for (int j = 0; j < 8; ++j)
            pa[kk2][j] = (_Float16)acc1[2 * kk2 + (j >> 2)][j & 3];

    float inv[4];
#pragma unroll
    for (int r = 0; r < 4; ++r) inv[r] = 1.0f / __shfl(sum, g * 4 + r);

    // ---- mm2: c2q[c][d] = sum_q P[c][q] query[q][d]
    f32x4 acc2[8] = {};
#pragma unroll
    for (int kk2 = 0; kk2 < 4; ++kk2)
#pragma unroll
        for (int ntD = 0; ntD < 8; ++ntD) {
            half8 qb = *(const half8*)&qT2[(ntD * 16 + l15) * QSTR + kk2 * 32 + 8 * g];
            acc2[ntD] = __builtin_amdgcn_mfma_f32_16x16x32_f16(pa[kk2], qb, acc2[ntD], 0, 0, 0);
        }
    __syncthreads();   // mloc complete; qrow/qT2 dead

    // ---- phase 4: Mloc, wv, Sloc; partial q2c -> ws
    float vm = mloc[t & 127];
    float m = vm;
#pragma unroll
    for (int off = 1; off < 64; off <<= 1) m = fmaxf(m, __shfl_xor(m, off));
    if (lane == 0) red[wave] = m;
    __syncthreads();
    float Mloc = red[0];
#pragma unroll
    for (int i = 1; i < 8; ++i) Mloc = fmaxf(Mloc, red[i]);
    float e = __expf(vm - Mloc);
    if (t < 128) wv[t] = e;
    float s = e;
#pragma unroll
    for (int off = 1; off < 64; off <<= 1) s += __shfl_xor(s, off);
    if (lane == 0) red[8 + wave] = s;
    __syncthreads();
    float Sloc = red[8] + red[9];   // waves 0,1 cover t=0..127

    const int grp = t >> 5, d4 = (t & 31) * 4;
    {
        const float* cb = ctxB + (size_t)(c0 + grp * 8) * Dn;
        f32x4 a = {};
#pragma unroll
        for (int i = 0; i < 8; ++i) {
            f32x4 cv = *(const f32x4*)(cb + (size_t)i * Dn + d4);
            float w = wv[grp * 8 + i];
            a.x += w * cv.x; a.y += w * cv.y; a.z += w * cv.z; a.w += w * cv.w;
        }
        *(f32x4*)&partf[grp * 128 + d4] = a;
    }
    __syncthreads();
    if (t < 128) {
        float s2 = 0.f;
#pragma unroll
        for (int g2 = 0; g2 < 16; ++g2) s2 += partf[g2 * 128 + t];
        ws_part[((size_t)(b * 8 + cg)) * 128 + t] = s2;
    }
    if (t == 0) {
        ws_ms[(b * 8 + cg) * 2 + 0] = Mloc;
        ws_ms[(b * 8 + cg) * 2 + 1] = Sloc;
    }
    __syncthreads();   // partf reads done -> cq may overlay

    // ---- phase 5: stage c2q into LDS
#pragma unroll
    for (int r = 0; r < 4; ++r) {
        int c = cw + g * 4 + r;
        float is = inv[r];
#pragma unroll
        for (int ntD = 0; ntD < 8; ++ntD)
            cq[c * CSTR + ntD * 16 + l15] = acc2[ntD][r] * is;
    }
    __syncthreads();

    // ---- phase 6: coalesced store of cols 1 (c2q) and 2 (ctx*c2q)
#pragma unroll
    for (int step = 0; step < 8; ++step) {
        int c = grp + step * 16;
        f32x4 q = *(const f32x4*)&cq[c * CSTR + d4];
        f32x4 cv = *(const f32x4*)(ctxB + (size_t)(c0 + c) * Dn + d4);
        float* orow = out + ((size_t)(b * Cn + c0 + c)) * 512;
        *(f32x4*)(orow + 128 + d4) = q;
        f32x4 pr;
        pr.x = cv.x * q.x; pr.y = cv.y * q.y; pr.z = cv.z * q.z; pr.w = cv.w * q.w;
        *(f32x4*)(orow + 256 + d4) = pr;
    }
}

// ---- K3: combine chunk-partials -> q2c; write cols 0 (ctx) and 3 (ctx*q2c)
__global__ __launch_bounds__(256) void k3_kernel(
    const float* __restrict__ ctx, const float* __restrict__ ws_part,
    const float* __restrict__ ws_ms, float* __restrict__ out)
{
    __shared__ float q2cs[128];
    const int ct = blockIdx.x, b = blockIdx.y, t = threadIdx.x;
    if (t < 128) {
        const float* ms = ws_ms + b * 16;
        float Mg = -3.4e38f;
#pragma unroll
        for (int i = 0; i < 8; ++i) Mg = fmaxf(Mg, ms[2 * i]);
        float num = 0.f, den = 0.f;
#pragma unroll
        for (int i = 0; i < 8; ++i) {
            float e = __expf(ms[2 * i] - Mg);
            num += e * ws_part[((size_t)(b * 8 + i)) * 128 + t];
            den += e * ms[2 * i + 1];
        }
        q2cs[t] = num / den;
    }
    __syncthreads();
    const float* cb = ctx + ((size_t)b * Cn + ct * 128) * Dn;
    float* ob = out + ((size_t)(b * Cn) + ct * 128) * 512;
    for (int step = 0; step < 16; ++step) {
        int c = (t >> 5) + step * 8, d4 = (t & 31) * 4;
        f32x4 v = *(const f32x4*)(cb + (size_t)c * Dn + d4);
        f32x4 q = *(const f32x4*)&q2cs[d4];
        *(f32x4*)(ob + (size_t)c * 512 + d4) = v;
        f32x4 w;
        w.x = v.x * q.x; w.y = v.y * q.y; w.z = v.z * q.z; w.w = v.w * q.w;
        *(f32x4*)(ob + (size_t)c * 512 + 384 + d4) = w;
    }
}

extern "C" void kernel_launch(void* const* d_in, const int* in_sizes, int n_in,
                              void* d_out, int out_size, void* d_ws, size_t ws_size,
                              hipStream_t stream) {
    const float* ctx  = (const float*)d_in[0];
    const float* qry  = (const float*)d_in[1];
    const float* W    = (const float*)d_in[2];
    const float* mask = (const float*)d_in[3];
    float* out = (float*)d_out;

    float* ws_part = (float*)d_ws;                    // 64*8*128 f32
    float* ws_ms   = ws_part + (size_t)Bn * 8 * 128;  // 64*8*2 f32

    k1_kernel<<<dim3(8, Bn), 512, 0, stream>>>(ctx, qry, W, mask, out, ws_part, ws_ms);
    k3_kernel<<<dim3(8, Bn), 256, 0, stream>>>(ctx, ws_part, ws_ms, out);
}

// Round 6
// 49.352 us; speedup vs baseline: 2.1256x; 1.0432x over previous
//
#include <hip/hip_runtime.h>

#define NEGINF -1000000000.0f

typedef __attribute__((ext_vector_type(4))) float f32x4;
typedef _Float16 half8 __attribute__((ext_vector_type(8)));
typedef _Float16 half4 __attribute__((ext_vector_type(4)));

constexpr int Bn = 64, Cn = 1024, Qn = 128, Dn = 128;
constexpr int QSTR = 136;   // halves; 272 B rows -> 2-way (free) b128 bank pattern
constexpr int CSTR = 132;   // floats; 528 B rows for cq bounce

// LDS map (bytes), total 72768 -> 2 blocks/CU:
//   0      qrow [128][136] fp16 = 34816  } overlaid (after mm2) by cq [128][132] f32 = 67584
//   34816  qT2  [128][136] fp16 = 34816  }   ... then partf [16][128] f32 = 8192 (after stores)
//   69632  wfull 384 f (1536)
//   71168  qts  128 f
//   71680  mloc 128 f
//   72192  wv   128 f
//   72704  red  16 f (64)

__global__ __launch_bounds__(512, 4) void k1_kernel(
    const float* __restrict__ ctx, const float* __restrict__ qry,
    const float* __restrict__ W, const float* __restrict__ mask,
    float* __restrict__ out, float* __restrict__ ws_part, float* __restrict__ ws_ms)
{
    __shared__ char smem[72768];
    _Float16* qrow = (_Float16*)smem;
    _Float16* qT2  = (_Float16*)(smem + 34816);
    float* wfull = (float*)(smem + 69632);
    float* qts   = (float*)(smem + 71168);
    float* mloc  = (float*)(smem + 71680);
    float* wv    = (float*)(smem + 72192);
    float* red   = (float*)(smem + 72704);
    float* cq    = (float*)smem;            // after mm2
    float* partf = (float*)(smem + 34816);  // after stores

    const int b = blockIdx.y, cg = blockIdx.x, c0 = cg * 128;
    const int t = threadIdx.x;
    const float* ctxB = ctx + (size_t)b * Cn * Dn;
    const float* qryB = qry + (size_t)b * Qn * Dn;

    if (t < 384) wfull[t] = W[t];
    __syncthreads();

    // ---- phase 1: stage query fp16 (row-major + bijection-transposed); qterm(+mask)
    {
        int q = t >> 2, h = t & 3;
        const float* qr = qryB + q * Dn + h * 32;
        int p = ((q >> 5) << 5) + 8 * ((q >> 2) & 3) + (q & 3) + 4 * ((q >> 4) & 1);
        float acc = 0.f;
        for (int j = 0; j < 32; j += 4) {
            f32x4 v = *(const f32x4*)(qr + j);
            int d = h * 32 + j;
            acc += v.x * wfull[128 + d] + v.y * wfull[128 + d + 1]
                 + v.z * wfull[128 + d + 2] + v.w * wfull[128 + d + 3];
            half4 hv;
            hv[0] = (_Float16)v.x; hv[1] = (_Float16)v.y;
            hv[2] = (_Float16)v.z; hv[3] = (_Float16)v.w;
            *(half4*)&qrow[q * QSTR + d] = hv;
            qT2[(d + 0) * QSTR + p] = hv[0];
            qT2[(d + 1) * QSTR + p] = hv[1];
            qT2[(d + 2) * QSTR + p] = hv[2];
            qT2[(d + 3) * QSTR + p] = hv[3];
        }
        acc += __shfl_xor(acc, 1);
        acc += __shfl_xor(acc, 2);
        if (h == 0) qts[q] = acc + (1.0f - mask[b * Qn + q]) * NEGINF;
    }
    __syncthreads();

    const int wave = t >> 6, lane = t & 63, g = lane >> 4, l15 = lane & 15;
    const int cw = wave * 16;
    const int cl = cw + l15;   // this lane's ctx row within the 128-tile

    // ---- phase 2: mm1  S^T[q][c] (fp16, no lo-split) with fused c_term
    f32x4 acc1[8] = {};
    float cterm = 0.f;
#pragma unroll
    for (int kk = 0; kk < 4; ++kk) {
        const int dbase = kk * 32 + g * 8;
        const float* pc = ctxB + (size_t)(c0 + cl) * Dn + dbase;
        f32x4 v0 = *(const f32x4*)pc, v1 = *(const f32x4*)(pc + 4);
        f32x4 s0 = *(const f32x4*)&wfull[256 + dbase], s1 = *(const f32x4*)&wfull[256 + dbase + 4];
        f32x4 c0w = *(const f32x4*)&wfull[dbase], c1w = *(const f32x4*)&wfull[dbase + 4];
        cterm += v0.x * c0w.x + v0.y * c0w.y + v0.z * c0w.z + v0.w * c0w.w
               + v1.x * c1w.x + v1.y * c1w.y + v1.z * c1w.z + v1.w * c1w.w;
        half8 ah;
        ah[0] = (_Float16)(v0.x * s0.x); ah[1] = (_Float16)(v0.y * s0.y);
        ah[2] = (_Float16)(v0.z * s0.z); ah[3] = (_Float16)(v0.w * s0.w);
        ah[4] = (_Float16)(v1.x * s1.x); ah[5] = (_Float16)(v1.y * s1.y);
        ah[6] = (_Float16)(v1.z * s1.z); ah[7] = (_Float16)(v1.w * s1.w);
#pragma unroll
        for (int mt = 0; mt < 8; ++mt) {
            half8 qf = *(const half8*)&qrow[(mt * 16 + l15) * QSTR + dbase];
            acc1[mt] = __builtin_amdgcn_mfma_f32_16x16x32_f16(qf, ah, acc1[mt], 0, 0, 0);
        }
    }
    cterm += __shfl_xor(cterm, 16);
    cterm += __shfl_xor(cterm, 32);   // all lanes: c_term for row cl

    // ---- phase 3: +q_term(+mask); softmax over q per column
#pragma unroll
    for (int mt = 0; mt < 8; ++mt)
#pragma unroll
        for (int r = 0; r < 4; ++r) acc1[mt][r] += qts[mt * 16 + g * 4 + r];

    float mx = -3.4e38f;
#pragma unroll
    for (int mt = 0; mt < 8; ++mt)
#pragma unroll
        for (int r = 0; r < 4; ++r) mx = fmaxf(mx, acc1[mt][r]);
    mx = fmaxf(mx, __shfl_xor(mx, 16));
    mx = fmaxf(mx, __shfl_xor(mx, 32));
    float sum = 0.f;
#pragma unroll
    for (int mt = 0; mt < 8; ++mt)
#pragma unroll
        for (int r = 0; r < 4; ++r) {
            float pv = __expf(acc1[mt][r] - mx);
            acc1[mt][r] = pv;
            sum += pv;
        }
    sum += __shfl_xor(sum, 16);
    sum += __shfl_xor(sum, 32);
    if (g == 0) mloc[cl] = mx + cterm;

    // pack P^T into A-frags (bijection k = 4g+(j&3)+16(j>>2)); inv colsums
    half8 pa[4];
#pragma unroll
    for (int kk2 = 0; kk2 < 4; ++kk2)
#pragma unroll
        for (int j = 0; j < 8; ++j)
            pa[kk2][j] = (_Float16)acc1[2 * kk2 + (j >> 2)][j & 3];

    float inv[4];
#pragma unroll
    for (int r = 0; r < 4; ++r) inv[r] = 1.0f / __shfl(sum, g * 4 + r);

    // ---- mm2: c2q[c][d] = sum_q P[c][q] query[q][d]
    f32x4 acc2[8] = {};
#pragma unroll
    for (int kk2 = 0; kk2 < 4; ++kk2)
#pragma unroll
        for (int ntD = 0; ntD < 8; ++ntD) {
            half8 qb = *(const half8*)&qT2[(ntD * 16 + l15) * QSTR + kk2 * 32 + 8 * g];
            acc2[ntD] = __builtin_amdgcn_mfma_f32_16x16x32_f16(pa[kk2], qb, acc2[ntD], 0, 0, 0);
        }
    __syncthreads();   // qrow/qT2 reads done; mloc complete

    // ---- phase 5: stage c2q into LDS (overlays qrow/qT2)
#pragma unroll
    for (int r = 0; r < 4; ++r) {
        int c = cw + g * 4 + r;
        float is = inv[r];
#pragma unroll
        for (int ntD = 0; ntD < 8; ++ntD)
            cq[c * CSTR + ntD * 16 + l15] = acc2[ntD][r] * is;
    }
    __syncthreads();

    // ---- phase 6: coalesced store of cols 0 (ctx), 1 (c2q), 2 (ctx*c2q)
    const int grp = t >> 5, d4 = (t & 31) * 4;
#pragma unroll
    for (int step = 0; step < 8; ++step) {
        int c = grp + step * 16;
        f32x4 q = *(const f32x4*)&cq[c * CSTR + d4];
        f32x4 cv = *(const f32x4*)(ctxB + (size_t)(c0 + c) * Dn + d4);
        float* orow = out + ((size_t)(b * Cn + c0 + c)) * 512;
        *(f32x4*)(orow + d4) = cv;
        *(f32x4*)(orow + 128 + d4) = q;
        f32x4 pr;
        pr.x = cv.x * q.x; pr.y = cv.y * q.y; pr.z = cv.z * q.z; pr.w = cv.w * q.w;
        *(f32x4*)(orow + 256 + d4) = pr;
    }

    // ---- phase 4a: Mloc, wv, Sloc  (first sync doubles as phase-6 completion)
    float vm = mloc[t & 127];
    float m = vm;
#pragma unroll
    for (int off = 1; off < 64; off <<= 1) m = fmaxf(m, __shfl_xor(m, off));
    if (lane == 0) red[wave] = m;
    __syncthreads();
    float Mloc = red[0];
#pragma unroll
    for (int i = 1; i < 8; ++i) Mloc = fmaxf(Mloc, red[i]);
    float e = __expf(vm - Mloc);
    if (t < 128) wv[t] = e;
    float s = e;
#pragma unroll
    for (int off = 1; off < 64; off <<= 1) s += __shfl_xor(s, off);
    if (lane == 0) red[8 + wave] = s;
    __syncthreads();
    float Sloc = red[8] + red[9];   // waves 0,1 cover t=0..127

    // ---- phase 4b: partial q2c -> ws (partf overlays cq region; stores done)
    {
        const float* cb = ctxB + (size_t)(c0 + grp * 8) * Dn;
        f32x4 a = {};
#pragma unroll
        for (int i = 0; i < 8; ++i) {
            f32x4 cv = *(const f32x4*)(cb + (size_t)i * Dn + d4);
            float w = wv[grp * 8 + i];
            a.x += w * cv.x; a.y += w * cv.y; a.z += w * cv.z; a.w += w * cv.w;
        }
        *(f32x4*)&partf[grp * 128 + d4] = a;
    }
    __syncthreads();
    if (t < 128) {
        float s2 = 0.f;
#pragma unroll
        for (int g2 = 0; g2 < 16; ++g2) s2 += partf[g2 * 128 + t];
        ws_part[((size_t)(b * 8 + cg)) * 128 + t] = s2;
    }
    if (t == 0) {
        ws_ms[(b * 8 + cg) * 2 + 0] = Mloc;
        ws_ms[(b * 8 + cg) * 2 + 1] = Sloc;
    }
}

// ---- K3: combine chunk-partials -> q2c; write col 3 (ctx*q2c) only
__global__ __launch_bounds__(256) void k3_kernel(
    const float* __restrict__ ctx, const float* __restrict__ ws_part,
    const float* __restrict__ ws_ms, float* __restrict__ out)
{
    __shared__ float q2cs[128];
    const int ct = blockIdx.x, b = blockIdx.y, t = threadIdx.x;
    if (t < 128) {
        const float* ms = ws_ms + b * 16;
        float Mg = -3.4e38f;
#pragma unroll
        for (int i = 0; i < 8; ++i) Mg = fmaxf(Mg, ms[2 * i]);
        float num = 0.f, den = 0.f;
#pragma unroll
        for (int i = 0; i < 8; ++i) {
            float e = __expf(ms[2 * i] - Mg);
            num += e * ws_part[((size_t)(b * 8 + i)) * 128 + t];
            den += e * ms[2 * i + 1];
        }
        q2cs[t] = num / den;
    }
    __syncthreads();
    const float* cb = ctx + ((size_t)b * Cn + ct * 128) * Dn;
    float* ob = out + ((size_t)(b * Cn) + ct * 128) * 512;
    for (int step = 0; step < 16; ++step) {
        int c = (t >> 5) + step * 8, d4 = (t & 31) * 4;
        f32x4 v = *(const f32x4*)(cb + (size_t)c * Dn + d4);
        f32x4 q = *(const f32x4*)&q2cs[d4];
        f32x4 w;
        w.x = v.x * q.x; w.y = v.y * q.y; w.z = v.z * q.z; w.w = v.w * q.w;
        *(f32x4*)(ob + (size_t)c * 512 + 384 + d4) = w;
    }
}

extern "C" void kernel_launch(void* const* d_in, const int* in_sizes, int n_in,
                              void* d_out, int out_size, void* d_ws, size_t ws_size,
                              hipStream_t stream) {
    const float* ctx  = (const float*)d_in[0];
    const float* qry  = (const float*)d_in[1];
    const float* W    = (const float*)d_in[2];
    const float* mask = (const float*)d_in[3];
    float* out = (float*)d_out;

    float* ws_part = (float*)d_ws;                    // 64*8*128 f32
    float* ws_ms   = ws_part + (size_t)Bn * 8 * 128;  // 64*8*2 f32

    k1_kernel<<<dim3(8, Bn), 512, 0, stream>>>(ctx, qry, W, mask, out, ws_part, ws_ms);
    k3_kernel<<<dim3(8, Bn), 256, 0, stream>>>(ctx, ws_part, ws_ms, out);
}